// Round 6
// baseline (121.520 us; speedup 1.0000x reference)
//
#include <hip/hip_runtime.h>
#include <math.h>

#define B_ 64
#define P_ 24564
#define G_ 48

// Workspace layout (total ~0.79 MB), everything fully overwritten every call (no memset):
//   [0]        unsigned long long bkey[B_][G_][NCH]   per-(b,g,chunk) best-prior keys
//   [786432]   float        pl[NBLK]                  per-block loss partials
//   [794624]   unsigned int pn[NBLK]                  per-block npos partials
//   [802816]   double       corrl[B_]                 per-image (correction + pl-slice) totals
//   [803328]   unsigned int corrn[B_]
// mrec is GONE: fix_kernel recomputes the per-prior top-2 bit-identically for the <=48
// priors it needs (top-2 over 48 distinct keys is order-independent; all ops deterministic).
constexpr int CH    = 768;              // chunk per block: 2048 blocks = exactly 8/CU
constexpr int NCH   = 32;               // 32*768 = 24576 >= P_
constexpr int PPT   = 3;
constexpr int NBLK  = NCH * B_;         // 2048
constexpr int ROW   = 68;               // kgrid row in u32: 64 entries + 4 pad (16B-aligned rows)

__device__ __forceinline__ float frcp(float x) { return __builtin_amdgcn_rcpf(x); }

// Smooth-ln repulsion term; identical in match (default) and fix (correction) so terms cancel.
__device__ __forceinline__ float loss_term(float4 pr, float4 l, float4 gb, float ga) {
    float cx = pr.x + l.x * 0.1f * pr.z;
    float cy = pr.y + l.y * 0.1f * pr.w;
    float w  = pr.z * expf(l.z * 0.2f);
    float h  = pr.w * expf(l.w * 0.2f);
    float dx1 = cx - w * 0.5f, dy1 = cy - h * 0.5f;
    float dx2 = cx + w * 0.5f, dy2 = cy + h * 0.5f;
    float ix1 = fmaxf(gb.x, dx1), iy1 = fmaxf(gb.y, dy1);
    float ix2 = fminf(gb.z, dx2), iy2 = fminf(gb.w, dy2);
    float iw = fmaxf(ix2 - ix1, 0.0f), ih = fmaxf(iy2 - iy1, 0.0f);
    float iogv = (iw * ih) * frcp(ga + 1e-7f);
    float r = 0.0f;
    if (iogv < 0.95f) {
        if (iogv < 0.5f)
            r = -logf(1.0f - iogv + 1e-7f);
        else
            r = (iogv - 0.5f) * 2.0f + 0.69314718055994531f;  // -ln(0.5)
    }
    return r;
}

// ---------------- K1: fused — top-2 per prior, per-gt block argmax, default loss ------------
// VALU-bound kernel. 2048 blocks x 256 thr = exactly 8 blocks/CU, LDS ~14.5 KB.
// KEY EXPERIMENT this round: VGPR_Count=24 proves the allocator remats the prior geometry
// (px1/py1/px2/py2/pa) inside the 48-iter g-loop (~2x VALU inflation: 45 vs 22 hand-counted
// slots/pair). asm-pin the 15 loop-invariant floats to block rematerialization;
// __launch_bounds__(256,2) gives the allocator headroom (<=64 VGPR still = 8 waves/SIMD).
__global__ __launch_bounds__(256, 2) void match_kernel(
    const float* __restrict__ pred_loc, const float* __restrict__ priors,
    const float* __restrict__ gt, unsigned long long* __restrict__ bkey,
    float* __restrict__ pl, unsigned int* __restrict__ pn) {
    const int b    = blockIdx.y;
    const int base = blockIdx.x * CH;
    const int tid  = threadIdx.x;

    __shared__ float4 sbox[G_];
    __shared__ float  sga[G_];
    __shared__ unsigned int kgrid[G_ * ROW];   // quad-reduced per-gt candidate keys (64/gt)
    __shared__ unsigned int pmax[G_][4];
    __shared__ float rs[4];
    __shared__ unsigned int rn[4];

    if (tid < G_) {
        const float* q = gt + ((size_t)b * G_ + tid) * 5;
        float x1 = q[0], y1 = q[1], x2 = q[2], y2 = q[3];
        sbox[tid] = make_float4(x1, y1, x2, y2);
        sga[tid]  = (x2 - x1) * (y2 - y1);
    }
    __syncthreads();

    float px1[PPT], py1[PPT], px2[PPT], py2[PPT], pa[PPT];
    unsigned int tb[PPT];  // 1023 - local_p (per-gt tie-break: lower p wins); lp<768 so 10 bits
#pragma unroll
    for (int j = 0; j < PPT; j++) {
        int lp = tid + 256 * j;
        int pc = min(base + lp, P_ - 1);  // clamped OOB dup loses tie-break to the real one
        float4 pr = ((const float4*)priors)[pc];
        float hx = pr.z * 0.5f, hy = pr.w * 0.5f;
        px1[j] = pr.x - hx; py1[j] = pr.y - hy;
        px2[j] = pr.x + hx; py2[j] = pr.y + hy;
        pa[j] = (px2[j] - px1[j]) * (py2[j] - py1[j]);
        tb[j] = (unsigned)(1023 - lp);
        // Opaque pin: forces each value into a VGPR and makes rematerialization impossible
        // (the allocator otherwise recomputes these from the raw float4 every g-iteration).
        asm volatile("" : "+v"(px1[j]), "+v"(py1[j]), "+v"(px2[j]), "+v"(py2[j]), "+v"(pa[j]));
    }

    unsigned int k1[PPT], k2[PPT];  // packed top-2 of r=inter/(ga+pa): (r&~0x3F)|(63-g)
#pragma unroll
    for (int j = 0; j < PPT; j++) { k1[j] = 0u; k2[j] = 0u; }

    const bool storer = (tid & 3) == 0;

#pragma unroll 8
    for (int g = 0; g < G_; g++) {
        float4 gb = sbox[g];
        float  ga = sga[g];
        unsigned int gmax = 0u;
#pragma unroll
        for (int j = 0; j < PPT; j++) {
            float ix1 = fmaxf(gb.x, px1[j]), iy1 = fmaxf(gb.y, py1[j]);
            float ix2 = fminf(gb.z, px2[j]), iy2 = fminf(gb.w, py2[j]);
            float iw = fmaxf(ix2 - ix1, 0.0f), ih = fmaxf(iy2 - iy1, 0.0f);
            float inter = iw * ih;
            // r = inter/(ga+pa) is a monotone transform of IoU=inter/(ga+pa-inter)
            float r = inter * frcp(ga + pa[j]);
            unsigned int vb = __float_as_uint(r);
            unsigned int pk = (vb & 0xFFFFFFC0u) | (unsigned)(63 - g);
            // top-2 update: new k2 = median(k1, k2, pk) under invariant k1 >= k2
            unsigned int nk2;
            asm("v_med3_u32 %0, %1, %2, %3" : "=v"(nk2) : "v"(k1[j]), "v"(k2[j]), "v"(pk));
            k2[j] = nk2;
            k1[j] = max(k1[j], pk);
            unsigned int gk = (vb & 0xFFFFFC00u) | tb[j];
            gmax = max(gmax, gk);
        }
        // quad reduce via LDS-pipe swizzles (xor1, xor2) — off the VALU critical resource
        unsigned int o1 = (unsigned int)__builtin_amdgcn_ds_swizzle((int)gmax, 0x041F);
        gmax = max(gmax, o1);
        unsigned int o2 = (unsigned int)__builtin_amdgcn_ds_swizzle((int)gmax, 0x081F);
        gmax = max(gmax, o2);
        if (storer) kgrid[g * ROW + (tid >> 2)] = gmax;
    }

    // per-prior epilogue: default contribution assumes NO override (bi=i1 -> rep=i2)
    float contrib = 0.0f;
    unsigned int np = 0;
#pragma unroll
    for (int j = 0; j < PPT; j++) {
        int p = base + tid + 256 * j;
        unsigned int i2 = 63u - (k2[j] & 63u);
        // r >= 1/3  <=>  IoU >= 0.5 ; truncated-key threshold (bits(1/3f) & ~0x3F)
        bool pos = (k1[j] >= 0x3EAAAA80u);
        if (p < P_ && pos) {
            float4 pr = ((const float4*)priors)[p];               // L1-hot reload
            float4 l  = ((const float4*)pred_loc)[(size_t)b * P_ + p];
            contrib += loss_term(pr, l, sbox[i2], sga[i2]);
            np++;
        }
    }

    const int lane = tid & 63, wv = tid >> 6;
    for (int off = 32; off; off >>= 1) {
        contrib += __shfl_down(contrib, off, 64);
        np      += __shfl_down(np, off, 64);
    }
    if (lane == 0) { rs[wv] = contrib; rn[wv] = np; }
    __syncthreads();  // kgrid + rs/rn visible

    // per-gt argmax within block: 4 readers per gt scan 16 entries each
    if (tid < 192) {
        int g = tid >> 2, qq = tid & 3;
        const uint4* row = (const uint4*)&kgrid[g * ROW + qq * 16];
        unsigned int m = 0u;
#pragma unroll
        for (int i = 0; i < 4; i++) {
            uint4 v = row[i];
            m = max(max(m, v.x), max(v.y, max(v.z, v.w)));
        }
        pmax[g][qq] = m;
    }
    __syncthreads();

    if (tid < G_) {
        unsigned int w = max(max(pmax[tid][0], pmax[tid][1]),
                             max(pmax[tid][2], pmax[tid][3]));
        int p = base + 1023 - (int)(w & 0x3FFu);
        p = min(p, P_ - 1);  // defensive; unreachable via tie-break
        float4 pr = ((const float4*)priors)[p];
        float hx = pr.z * 0.5f, hy = pr.w * 0.5f;
        float qx1 = pr.x - hx, qy1 = pr.y - hy, qx2 = pr.x + hx, qy2 = pr.y + hy;
        float pae = (qx2 - qx1) * (qy2 - qy1);
        float4 gb = sbox[tid];
        float ix1 = fmaxf(gb.x, qx1), iy1 = fmaxf(gb.y, qy1);
        float ix2 = fminf(gb.z, qx2), iy2 = fminf(gb.w, qy2);
        float iw = fmaxf(ix2 - ix1, 0.0f), ih = fmaxf(iy2 - iy1, 0.0f);
        float inter = iw * ih;
        // exact (bit-stable across blocks) IoU-form key for cross-block comparison
        float v = inter * frcp(sga[tid] + pae - inter);
        // layout [b][g][chunk]: fix kernel reads each (b,g)'s 32 keys contiguously;
        // plain store (every slot written every call -> no init/memset needed)
        bkey[((size_t)b * G_ + tid) * NCH + blockIdx.x] =
            ((unsigned long long)__float_as_uint(v) << 32) |
            (unsigned long long)(0xFFFFFFFFu - (unsigned)p);
    }

    if (tid == 0) {
        pl[b * NCH + blockIdx.x] = rs[0] + rs[1] + rs[2] + rs[3];
        pn[b * NCH + blockIdx.x] = rn[0] + rn[1] + rn[2] + rn[3];
    }
}

// ---------------- K2: per-image bkey reduce + override corrections + pl/pn fold -------------
// Recomputes the best prior's top-2 keys bit-identically (max / second-max over 48 distinct
// keys is order-independent; fmax/fmin/rcp/med3 are deterministic), so mrec isn't needed.
// Also folds this image's pl/pn chunk partials so final_kernel only reduces 64 entries.
__global__ __launch_bounds__(64) void fix_kernel(
    const float* __restrict__ pred_loc, const float* __restrict__ priors,
    const float* __restrict__ gt, const unsigned long long* __restrict__ bkey,
    const float* __restrict__ pl, const unsigned int* __restrict__ pn,
    double* __restrict__ corrl, unsigned int* __restrict__ corrn) {
    const int b = blockIdx.x, t = threadIdx.x;
    __shared__ float4 sbox[G_];
    __shared__ float  sga[G_];
    __shared__ int sp[G_];

    if (t < G_) {
        const float* q = gt + ((size_t)b * G_ + t) * 5;
        float x1 = q[0], y1 = q[1], x2 = q[2], y2 = q[3];
        sbox[t] = make_float4(x1, y1, x2, y2);
        sga[t]  = (x2 - x1) * (y2 - y1);
    }
    // fold this image's chunk partials (NCH == 32 <= 64 threads)
    float  pls = 0.0f;
    unsigned int pns = 0u;
    if (t < NCH) { pls = pl[b * NCH + t]; pns = pn[b * NCH + t]; }

    int p = -1;
    if (t < G_) {
        const unsigned long long* row = bkey + ((size_t)b * G_ + t) * NCH;
        unsigned long long m = 0ull;
#pragma unroll
        for (int c = 0; c < NCH; c++) m = max(m, row[c]);
        p = (int)(0xFFFFFFFFu - (unsigned)(m & 0xFFFFFFFFull));
        sp[t] = p;
    }
    __syncthreads();

    double delta = 0.0;
    unsigned int dn = 0;
    if (t < G_) {
        // last-write-wins: t is alive iff no larger t' shares the same best prior
        bool alive = true;
        for (int d = t + 1; d < G_; d++)
            if (sp[d] == p) alive = false;
        if (alive) {
            // recompute prior p's top-2 over all gts (bit-identical to match's tournament)
            float4 pr = ((const float4*)priors)[p];
            float hx = pr.z * 0.5f, hy = pr.w * 0.5f;
            float px1 = pr.x - hx, py1 = pr.y - hy, px2 = pr.x + hx, py2 = pr.y + hy;
            float pa = (px2 - px1) * (py2 - py1);
            unsigned int k1 = 0u, k2 = 0u;
#pragma unroll 8
            for (int g = 0; g < G_; g++) {
                float4 gb = sbox[g];
                float ix1 = fmaxf(gb.x, px1), iy1 = fmaxf(gb.y, py1);
                float ix2 = fminf(gb.z, px2), iy2 = fminf(gb.w, py2);
                float iw = fmaxf(ix2 - ix1, 0.0f), ih = fmaxf(iy2 - iy1, 0.0f);
                float inter = iw * ih;
                float r = inter * frcp(sga[g] + pa);
                unsigned int vb = __float_as_uint(r);
                unsigned int pk = (vb & 0xFFFFFFC0u) | (unsigned)(63 - g);
                unsigned int nk2;
                asm("v_med3_u32 %0, %1, %2, %3" : "=v"(nk2) : "v"(k1), "v"(k2), "v"(pk));
                k2 = nk2;
                k1 = max(k1, pk);
            }
            int i1 = (int)(63u - (k1 & 63u)), i2 = (int)(63u - (k2 & 63u));
            bool pos0 = (k1 >= 0x3EAAAA80u);
            int ri = (t == i1) ? i2 : i1;   // override bi=t -> rep flips to i1 unless t==i1
            float4 l = ((const float4*)pred_loc)[(size_t)b * P_ + p];
            float cnew = loss_term(pr, l, sbox[ri], sga[ri]);
            float cold = 0.0f;
            if (pos0) {
                cold = loss_term(pr, l, sbox[i2], sga[i2]);   // cancels match's default term
            } else {
                dn = 1;                                        // prior newly positive
            }
            delta = (double)cnew - (double)cold;
        }
    }
    double acc = delta + (double)pls;
    unsigned int nn = dn + pns;
    for (int off = 32; off; off >>= 1) {
        acc += __shfl_down(acc, off, 64);
        nn  += __shfl_down(nn, off, 64);
    }
    if (t == 0) { corrl[b] = acc; corrn[b] = nn; }
}

// ---------------- K3: final reduction (64 per-image totals -> scalar) -----------------------
__global__ __launch_bounds__(64) void final_kernel(
    const double* __restrict__ corrl, const unsigned int* __restrict__ corrn,
    float* __restrict__ out) {
    const int t = threadIdx.x;
    double acc = corrl[t];        // B_ == 64 == blockDim
    unsigned int n = corrn[t];
    for (int off = 32; off; off >>= 1) {
        acc += __shfl_down(acc, off, 64);
        n   += __shfl_down(n, off, 64);
    }
    if (t == 0) out[0] = (float)(acc / (double)n);
}

extern "C" void kernel_launch(void* const* d_in, const int* in_sizes, int n_in,
                              void* d_out, int out_size, void* d_ws, size_t ws_size,
                              hipStream_t stream) {
    const float* pred_loc = (const float*)d_in[0];  // [B,P,4]
    const float* priors   = (const float*)d_in[1];  // [P,4]
    const float* gt       = (const float*)d_in[2];  // [B,G,5]
    float* out = (float*)d_out;

    char* ws = (char*)d_ws;
    unsigned long long* bkey = (unsigned long long*)ws;                   // 786432 B
    float*        pl    = (float*)(ws + 786432);                          // 8192 B
    unsigned int* pn    = (unsigned int*)(ws + 794624);                   // 8192 B
    double*       corrl = (double*)(ws + 802816);                         // 512 B
    unsigned int* corrn = (unsigned int*)(ws + 803328);                   // 256 B

    dim3 g1(NCH, B_);
    match_kernel<<<g1, 256, 0, stream>>>(pred_loc, priors, gt, bkey, pl, pn);

    fix_kernel<<<B_, 64, 0, stream>>>(pred_loc, priors, gt, bkey, pl, pn, corrl, corrn);

    final_kernel<<<1, 64, 0, stream>>>(corrl, corrn, out);
}

// Round 7
// 120.979 us; speedup vs baseline: 1.0045x; 1.0045x over previous
//
#include <hip/hip_runtime.h>
#include <math.h>

#define B_ 64
#define P_ 24564
#define G_ 48

// Workspace layout (total ~0.79 MB), everything fully overwritten every call (no memset):
//   [0]        unsigned long long bkey[B_][G_][NCH]   per-(b,g,chunk) best-prior keys
//   [786432]   float        pl[NBLK]                  per-block loss partials
//   [794624]   unsigned int pn[NBLK]                  per-block npos partials
//   [802816]   double       corrl[B_]                 per-image (correction + pl-slice) totals
//   [803328]   unsigned int corrn[B_]
// mrec is GONE: fix_kernel recomputes the per-prior top-2 bit-identically for the <=48
// priors it needs (top-2 over 48 distinct keys is order-independent; all ops deterministic).
constexpr int CH    = 768;              // chunk per block: 2048 blocks = exactly 8/CU
constexpr int NCH   = 32;               // 32*768 = 24576 >= P_
constexpr int PPT   = 3;
constexpr int NBLK  = NCH * B_;         // 2048
constexpr int ROW   = 68;               // kgrid row in u32: 64 entries + 4 pad (16B-aligned rows)

__device__ __forceinline__ float frcp(float x) { return __builtin_amdgcn_rcpf(x); }

// Smooth-ln repulsion term; identical in match (default) and fix (correction) so terms cancel.
__device__ __forceinline__ float loss_term(float4 pr, float4 l, float4 gb, float ga) {
    float cx = pr.x + l.x * 0.1f * pr.z;
    float cy = pr.y + l.y * 0.1f * pr.w;
    float w  = pr.z * expf(l.z * 0.2f);
    float h  = pr.w * expf(l.w * 0.2f);
    float dx1 = cx - w * 0.5f, dy1 = cy - h * 0.5f;
    float dx2 = cx + w * 0.5f, dy2 = cy + h * 0.5f;
    float ix1 = fmaxf(gb.x, dx1), iy1 = fmaxf(gb.y, dy1);
    float ix2 = fminf(gb.z, dx2), iy2 = fminf(gb.w, dy2);
    float iw = fmaxf(ix2 - ix1, 0.0f), ih = fmaxf(iy2 - iy1, 0.0f);
    float iogv = (iw * ih) * frcp(ga + 1e-7f);
    float r = 0.0f;
    if (iogv < 0.95f) {
        if (iogv < 0.5f)
            r = -logf(1.0f - iogv + 1e-7f);
        else
            r = (iogv - 0.5f) * 2.0f + 0.69314718055994531f;  // -ln(0.5)
    }
    return r;
}

// ---------------- K1: fused — top-2 per prior, per-gt block argmax, default loss ------------
// VALU-bound kernel. 2048 blocks x 256 thr = exactly 8 blocks/CU, LDS ~14.5 KB.
// This round: (a) med3 via min/max expression (LLVM's med3 combine emits v_med3_u32 WITHOUT
// the inline-asm copy overhead and without blocking the scheduler), (b) one-ahead software
// prefetch of gb/ga to break the per-g ds_read->use latency chain (VGPR=24 build couldn't
// pipeline the unrolled loads), (c) pins removed (proven null in R6).
__global__ __launch_bounds__(256) void match_kernel(
    const float* __restrict__ pred_loc, const float* __restrict__ priors,
    const float* __restrict__ gt, unsigned long long* __restrict__ bkey,
    float* __restrict__ pl, unsigned int* __restrict__ pn) {
    const int b    = blockIdx.y;
    const int base = blockIdx.x * CH;
    const int tid  = threadIdx.x;

    __shared__ float4 sbox[G_];
    __shared__ float  sga[G_];
    __shared__ unsigned int kgrid[G_ * ROW];   // quad-reduced per-gt candidate keys (64/gt)
    __shared__ unsigned int pmax[G_][4];
    __shared__ float rs[4];
    __shared__ unsigned int rn[4];

    if (tid < G_) {
        const float* q = gt + ((size_t)b * G_ + tid) * 5;
        float x1 = q[0], y1 = q[1], x2 = q[2], y2 = q[3];
        sbox[tid] = make_float4(x1, y1, x2, y2);
        sga[tid]  = (x2 - x1) * (y2 - y1);
    }
    __syncthreads();

    float px1[PPT], py1[PPT], px2[PPT], py2[PPT], pa[PPT];
    unsigned int tb[PPT];  // 1023 - local_p (per-gt tie-break: lower p wins); lp<768 so 10 bits
#pragma unroll
    for (int j = 0; j < PPT; j++) {
        int lp = tid + 256 * j;
        int pc = min(base + lp, P_ - 1);  // clamped OOB dup loses tie-break to the real one
        float4 pr = ((const float4*)priors)[pc];
        float hx = pr.z * 0.5f, hy = pr.w * 0.5f;
        px1[j] = pr.x - hx; py1[j] = pr.y - hy;
        px2[j] = pr.x + hx; py2[j] = pr.y + hy;
        pa[j] = (px2[j] - px1[j]) * (py2[j] - py1[j]);
        tb[j] = (unsigned)(1023 - lp);
    }

    unsigned int k1[PPT], k2[PPT];  // packed top-2 of r=inter/(ga+pa): (r&~0x3F)|(63-g)
#pragma unroll
    for (int j = 0; j < PPT; j++) { k1[j] = 0u; k2[j] = 0u; }

    const bool storer = (tid & 3) == 0;

    // software-pipelined g-loop: load g+1's box while computing g
    float4 gb = sbox[0];
    float  ga = sga[0];
#pragma unroll 4
    for (int g = 0; g < G_; g++) {
        const int gn = (g + 1 < G_) ? g + 1 : g;
        float4 gbn = sbox[gn];
        float  gan = sga[gn];
        unsigned int gmax = 0u;
#pragma unroll
        for (int j = 0; j < PPT; j++) {
            float ix1 = fmaxf(gb.x, px1[j]), iy1 = fmaxf(gb.y, py1[j]);
            float ix2 = fminf(gb.z, px2[j]), iy2 = fminf(gb.w, py2[j]);
            float iw = fmaxf(ix2 - ix1, 0.0f), ih = fmaxf(iy2 - iy1, 0.0f);
            float inter = iw * ih;
            // r = inter/(ga+pa) is a monotone transform of IoU=inter/(ga+pa-inter)
            float r = inter * frcp(ga + pa[j]);
            unsigned int vb = __float_as_uint(r);
            unsigned int pk = (vb & 0xFFFFFFC0u) | (unsigned)(63 - g);
            // top-2 update; min/max form is bit-identical to med3(k1,k2,pk) under k1>=k2,
            // and LLVM's med3 combine emits v_med3_u32 without asm-copy overhead
            k2[j] = min(max(k2[j], pk), k1[j]);
            k1[j] = max(k1[j], pk);
            unsigned int gk = (vb & 0xFFFFFC00u) | tb[j];
            gmax = max(gmax, gk);
        }
        // quad reduce via LDS-pipe swizzles (xor1, xor2) — off the VALU critical resource
        unsigned int o1 = (unsigned int)__builtin_amdgcn_ds_swizzle((int)gmax, 0x041F);
        gmax = max(gmax, o1);
        unsigned int o2 = (unsigned int)__builtin_amdgcn_ds_swizzle((int)gmax, 0x081F);
        gmax = max(gmax, o2);
        if (storer) kgrid[g * ROW + (tid >> 2)] = gmax;
        gb = gbn; ga = gan;
    }

    // per-prior epilogue: default contribution assumes NO override (bi=i1 -> rep=i2)
    float contrib = 0.0f;
    unsigned int np = 0;
#pragma unroll
    for (int j = 0; j < PPT; j++) {
        int p = base + tid + 256 * j;
        unsigned int i2 = 63u - (k2[j] & 63u);
        // r >= 1/3  <=>  IoU >= 0.5 ; truncated-key threshold (bits(1/3f) & ~0x3F)
        bool pos = (k1[j] >= 0x3EAAAA80u);
        if (p < P_ && pos) {
            float4 pr = ((const float4*)priors)[p];               // L1-hot reload
            float4 l  = ((const float4*)pred_loc)[(size_t)b * P_ + p];
            contrib += loss_term(pr, l, sbox[i2], sga[i2]);
            np++;
        }
    }

    const int lane = tid & 63, wv = tid >> 6;
    for (int off = 32; off; off >>= 1) {
        contrib += __shfl_down(contrib, off, 64);
        np      += __shfl_down(np, off, 64);
    }
    if (lane == 0) { rs[wv] = contrib; rn[wv] = np; }
    __syncthreads();  // kgrid + rs/rn visible

    // per-gt argmax within block: 4 readers per gt scan 16 entries each
    if (tid < 192) {
        int g = tid >> 2, qq = tid & 3;
        const uint4* row = (const uint4*)&kgrid[g * ROW + qq * 16];
        unsigned int m = 0u;
#pragma unroll
        for (int i = 0; i < 4; i++) {
            uint4 v = row[i];
            m = max(max(m, v.x), max(v.y, max(v.z, v.w)));
        }
        pmax[g][qq] = m;
    }
    __syncthreads();

    if (tid < G_) {
        unsigned int w = max(max(pmax[tid][0], pmax[tid][1]),
                             max(pmax[tid][2], pmax[tid][3]));
        int p = base + 1023 - (int)(w & 0x3FFu);
        p = min(p, P_ - 1);  // defensive; unreachable via tie-break
        float4 pr = ((const float4*)priors)[p];
        float hx = pr.z * 0.5f, hy = pr.w * 0.5f;
        float qx1 = pr.x - hx, qy1 = pr.y - hy, qx2 = pr.x + hx, qy2 = pr.y + hy;
        float pae = (qx2 - qx1) * (qy2 - qy1);
        float4 gb2 = sbox[tid];
        float ix1 = fmaxf(gb2.x, qx1), iy1 = fmaxf(gb2.y, qy1);
        float ix2 = fminf(gb2.z, qx2), iy2 = fminf(gb2.w, qy2);
        float iw = fmaxf(ix2 - ix1, 0.0f), ih = fmaxf(iy2 - iy1, 0.0f);
        float inter = iw * ih;
        // exact (bit-stable across blocks) IoU-form key for cross-block comparison
        float v = inter * frcp(sga[tid] + pae - inter);
        // layout [b][g][chunk]: fix kernel reads each (b,g)'s 32 keys contiguously;
        // plain store (every slot written every call -> no init/memset needed)
        bkey[((size_t)b * G_ + tid) * NCH + blockIdx.x] =
            ((unsigned long long)__float_as_uint(v) << 32) |
            (unsigned long long)(0xFFFFFFFFu - (unsigned)p);
    }

    if (tid == 0) {
        pl[b * NCH + blockIdx.x] = rs[0] + rs[1] + rs[2] + rs[3];
        pn[b * NCH + blockIdx.x] = rn[0] + rn[1] + rn[2] + rn[3];
    }
}

// ---------------- K2: per-image bkey reduce + override corrections + pl/pn fold -------------
// Recomputes the best prior's top-2 keys bit-identically (max / second-max over 48 distinct
// keys is order-independent; fmax/fmin/rcp/min/max are deterministic), so mrec isn't needed.
// Also folds this image's pl/pn chunk partials so final_kernel only reduces 64 entries.
__global__ __launch_bounds__(64) void fix_kernel(
    const float* __restrict__ pred_loc, const float* __restrict__ priors,
    const float* __restrict__ gt, const unsigned long long* __restrict__ bkey,
    const float* __restrict__ pl, const unsigned int* __restrict__ pn,
    double* __restrict__ corrl, unsigned int* __restrict__ corrn) {
    const int b = blockIdx.x, t = threadIdx.x;
    __shared__ float4 sbox[G_];
    __shared__ float  sga[G_];
    __shared__ int sp[G_];

    if (t < G_) {
        const float* q = gt + ((size_t)b * G_ + t) * 5;
        float x1 = q[0], y1 = q[1], x2 = q[2], y2 = q[3];
        sbox[t] = make_float4(x1, y1, x2, y2);
        sga[t]  = (x2 - x1) * (y2 - y1);
    }
    // fold this image's chunk partials (NCH == 32 <= 64 threads)
    float  pls = 0.0f;
    unsigned int pns = 0u;
    if (t < NCH) { pls = pl[b * NCH + t]; pns = pn[b * NCH + t]; }

    int p = -1;
    if (t < G_) {
        const unsigned long long* row = bkey + ((size_t)b * G_ + t) * NCH;
        unsigned long long m = 0ull;
#pragma unroll
        for (int c = 0; c < NCH; c++) m = max(m, row[c]);
        p = (int)(0xFFFFFFFFu - (unsigned)(m & 0xFFFFFFFFull));
        sp[t] = p;
    }
    __syncthreads();

    double delta = 0.0;
    unsigned int dn = 0;
    if (t < G_) {
        // last-write-wins: t is alive iff no larger t' shares the same best prior
        bool alive = true;
        for (int d = t + 1; d < G_; d++)
            if (sp[d] == p) alive = false;
        if (alive) {
            // recompute prior p's top-2 over all gts (bit-identical to match's tournament)
            float4 pr = ((const float4*)priors)[p];
            float hx = pr.z * 0.5f, hy = pr.w * 0.5f;
            float px1 = pr.x - hx, py1 = pr.y - hy, px2 = pr.x + hx, py2 = pr.y + hy;
            float pa = (px2 - px1) * (py2 - py1);
            unsigned int k1 = 0u, k2 = 0u;
#pragma unroll 8
            for (int g = 0; g < G_; g++) {
                float4 gb = sbox[g];
                float ix1 = fmaxf(gb.x, px1), iy1 = fmaxf(gb.y, py1);
                float ix2 = fminf(gb.z, px2), iy2 = fminf(gb.w, py2);
                float iw = fmaxf(ix2 - ix1, 0.0f), ih = fmaxf(iy2 - iy1, 0.0f);
                float inter = iw * ih;
                float r = inter * frcp(sga[g] + pa);
                unsigned int vb = __float_as_uint(r);
                unsigned int pk = (vb & 0xFFFFFFC0u) | (unsigned)(63 - g);
                k2 = min(max(k2, pk), k1);
                k1 = max(k1, pk);
            }
            int i1 = (int)(63u - (k1 & 63u)), i2 = (int)(63u - (k2 & 63u));
            bool pos0 = (k1 >= 0x3EAAAA80u);
            int ri = (t == i1) ? i2 : i1;   // override bi=t -> rep flips to i1 unless t==i1
            float4 l = ((const float4*)pred_loc)[(size_t)b * P_ + p];
            float cnew = loss_term(pr, l, sbox[ri], sga[ri]);
            float cold = 0.0f;
            if (pos0) {
                cold = loss_term(pr, l, sbox[i2], sga[i2]);   // cancels match's default term
            } else {
                dn = 1;                                        // prior newly positive
            }
            delta = (double)cnew - (double)cold;
        }
    }
    double acc = delta + (double)pls;
    unsigned int nn = dn + pns;
    for (int off = 32; off; off >>= 1) {
        acc += __shfl_down(acc, off, 64);
        nn  += __shfl_down(nn, off, 64);
    }
    if (t == 0) { corrl[b] = acc; corrn[b] = nn; }
}

// ---------------- K3: final reduction (64 per-image totals -> scalar) -----------------------
__global__ __launch_bounds__(64) void final_kernel(
    const double* __restrict__ corrl, const unsigned int* __restrict__ corrn,
    float* __restrict__ out) {
    const int t = threadIdx.x;
    double acc = corrl[t];        // B_ == 64 == blockDim
    unsigned int n = corrn[t];
    for (int off = 32; off; off >>= 1) {
        acc += __shfl_down(acc, off, 64);
        n   += __shfl_down(n, off, 64);
    }
    if (t == 0) out[0] = (float)(acc / (double)n);
}

extern "C" void kernel_launch(void* const* d_in, const int* in_sizes, int n_in,
                              void* d_out, int out_size, void* d_ws, size_t ws_size,
                              hipStream_t stream) {
    const float* pred_loc = (const float*)d_in[0];  // [B,P,4]
    const float* priors   = (const float*)d_in[1];  // [P,4]
    const float* gt       = (const float*)d_in[2];  // [B,G,5]
    float* out = (float*)d_out;

    char* ws = (char*)d_ws;
    unsigned long long* bkey = (unsigned long long*)ws;                   // 786432 B
    float*        pl    = (float*)(ws + 786432);                          // 8192 B
    unsigned int* pn    = (unsigned int*)(ws + 794624);                   // 8192 B
    double*       corrl = (double*)(ws + 802816);                         // 512 B
    unsigned int* corrn = (unsigned int*)(ws + 803328);                   // 256 B

    dim3 g1(NCH, B_);
    match_kernel<<<g1, 256, 0, stream>>>(pred_loc, priors, gt, bkey, pl, pn);

    fix_kernel<<<B_, 64, 0, stream>>>(pred_loc, priors, gt, bkey, pl, pn, corrl, corrn);

    final_kernel<<<1, 64, 0, stream>>>(corrl, corrn, out);
}

// Round 8
// 117.578 us; speedup vs baseline: 1.0335x; 1.0289x over previous
//
#include <hip/hip_runtime.h>
#include <math.h>

#define B_ 64
#define P_ 24564
#define G_ 48

// Workspace layout (total ~0.79 MB), everything fully overwritten every call (no memset):
//   [0]        unsigned long long bkey[B_][G_][NCH]   per-(b,g,chunk) best-prior keys
//   [786432]   float        pl[NBLK]                  per-block loss partials
//   [794624]   unsigned int pn[NBLK]                  per-block npos partials
//   [802816]   double       corrl[B_]                 per-image (correction + pl-slice) totals
//   [803328]   unsigned int corrn[B_]
// mrec is GONE: fix_kernel recomputes the per-prior top-2 bit-identically for the <=48
// priors it needs (top-2 over 48 distinct keys is order-independent; all ops deterministic).
constexpr int CH    = 768;              // chunk per block: 2048 blocks = exactly 8/CU
constexpr int NCH   = 32;               // 32*768 = 24576 >= P_
constexpr int PPT   = 3;
constexpr int NBLK  = NCH * B_;         // 2048
constexpr int ROW   = 68;               // kgrid row in u32: 64 entries + 4 pad (16B-aligned rows)

__device__ __forceinline__ float frcp(float x) { return __builtin_amdgcn_rcpf(x); }

// Smooth-ln repulsion term; identical in match (default) and fix (correction) so terms cancel.
__device__ __forceinline__ float loss_term(float4 pr, float4 l, float4 gb, float ga) {
    float cx = pr.x + l.x * 0.1f * pr.z;
    float cy = pr.y + l.y * 0.1f * pr.w;
    float w  = pr.z * expf(l.z * 0.2f);
    float h  = pr.w * expf(l.w * 0.2f);
    float dx1 = cx - w * 0.5f, dy1 = cy - h * 0.5f;
    float dx2 = cx + w * 0.5f, dy2 = cy + h * 0.5f;
    float ix1 = fmaxf(gb.x, dx1), iy1 = fmaxf(gb.y, dy1);
    float ix2 = fminf(gb.z, dx2), iy2 = fminf(gb.w, dy2);
    float iw = fmaxf(ix2 - ix1, 0.0f), ih = fmaxf(iy2 - iy1, 0.0f);
    float iogv = (iw * ih) * frcp(ga + 1e-7f);
    float r = 0.0f;
    if (iogv < 0.95f) {
        if (iogv < 0.5f)
            r = -logf(1.0f - iogv + 1e-7f);
        else
            r = (iogv - 0.5f) * 2.0f + 0.69314718055994531f;  // -ln(0.5)
    }
    return r;
}

// ---------------- K1: fused — top-2 per prior, per-gt block argmax, default loss ------------
// VALU-bound kernel; measured ~45 issue-slots/pair vs 17 ops in source (2.3x inflation that
// survived launch-bounds/pins/expression-form probes). This round PINS the instruction stream:
// the per-pair body is one 17-instruction asm block (bit-identical values & op order to R5's
// intrinsic form). Masks hoisted to SGPRs; gid = 63-g as one v_mov per g.
__global__ __launch_bounds__(256) void match_kernel(
    const float* __restrict__ pred_loc, const float* __restrict__ priors,
    const float* __restrict__ gt, unsigned long long* __restrict__ bkey,
    float* __restrict__ pl, unsigned int* __restrict__ pn) {
    const int b    = blockIdx.y;
    const int base = blockIdx.x * CH;
    const int tid  = threadIdx.x;

    __shared__ float4 sbox[G_];
    __shared__ float  sga[G_];
    __shared__ unsigned int kgrid[G_ * ROW];   // quad-reduced per-gt candidate keys (64/gt)
    __shared__ unsigned int pmax[G_][4];
    __shared__ float rs[4];
    __shared__ unsigned int rn[4];

    if (tid < G_) {
        const float* q = gt + ((size_t)b * G_ + tid) * 5;
        float x1 = q[0], y1 = q[1], x2 = q[2], y2 = q[3];
        sbox[tid] = make_float4(x1, y1, x2, y2);
        sga[tid]  = (x2 - x1) * (y2 - y1);
    }
    __syncthreads();

    float px1[PPT], py1[PPT], px2[PPT], py2[PPT], pa[PPT];
    unsigned int tb[PPT];  // 1023 - local_p (per-gt tie-break: lower p wins); lp<768 so 10 bits
#pragma unroll
    for (int j = 0; j < PPT; j++) {
        int lp = tid + 256 * j;
        int pc = min(base + lp, P_ - 1);  // clamped OOB dup loses tie-break to the real one
        float4 pr = ((const float4*)priors)[pc];
        float hx = pr.z * 0.5f, hy = pr.w * 0.5f;
        px1[j] = pr.x - hx; py1[j] = pr.y - hy;
        px2[j] = pr.x + hx; py2[j] = pr.y + hy;
        pa[j] = (px2[j] - px1[j]) * (py2[j] - py1[j]);
        tb[j] = (unsigned)(1023 - lp);
    }

    unsigned int k1[PPT], k2[PPT];  // packed top-2 of r=inter/(ga+pa): (r&~0x3F)|(63-g)
#pragma unroll
    for (int j = 0; j < PPT; j++) { k1[j] = 0u; k2[j] = 0u; }

    const bool storer = (tid & 3) == 0;

#pragma unroll 8
    for (int g = 0; g < G_; g++) {
        float4 gb = sbox[g];
        float  ga = sga[g];
        unsigned int gid = 63u - (unsigned)g;
        unsigned int gmax = 0u;
#pragma unroll
        for (int j = 0; j < PPT; j++) {
            // Pinned 17-inst pair body; values/order bit-identical to the intrinsic form:
            //   ix1=max(gb.x,px1) iy1=max(gb.y,py1) ix2=min(gb.z,px2) iy2=min(gb.w,py2)
            //   iw=max(ix2-ix1,0) ih=max(iy2-iy1,0) inter=iw*ih r=inter*rcp(ga+pa)
            //   pk=(bits(r)&0xFFFFFFC0)|(63-g); k2=med3(k1,k2,pk); k1=max(k1,pk)
            //   gk=(bits(r)&0xFFFFFC00)|tb;     gmax=max(gmax,gk)
            float a0, a1, a2, a3;
            unsigned int u0, u1;
            asm("v_max_f32 %[a0], %[gx], %[px1]\n\t"
                "v_max_f32 %[a1], %[gy], %[py1]\n\t"
                "v_min_f32 %[a2], %[gz], %[px2]\n\t"
                "v_min_f32 %[a3], %[gw], %[py2]\n\t"
                "v_sub_f32 %[a2], %[a2], %[a0]\n\t"
                "v_sub_f32 %[a3], %[a3], %[a1]\n\t"
                "v_max_f32 %[a2], 0, %[a2]\n\t"
                "v_max_f32 %[a3], 0, %[a3]\n\t"
                "v_mul_f32 %[a2], %[a2], %[a3]\n\t"
                "v_add_f32 %[a3], %[ga], %[pa]\n\t"
                "v_rcp_f32 %[a3], %[a3]\n\t"
                "v_mul_f32 %[a2], %[a2], %[a3]\n\t"
                "v_and_or_b32 %[u0], %[a2], %[smp], %[gid]\n\t"
                "v_med3_u32 %[k2], %[k1], %[k2], %[u0]\n\t"
                "v_max_u32 %[k1], %[k1], %[u0]\n\t"
                "v_and_or_b32 %[u1], %[a2], %[smg], %[tb]\n\t"
                "v_max_u32 %[gmax], %[gmax], %[u1]"
                : [a0] "=&v"(a0), [a1] "=&v"(a1), [a2] "=&v"(a2), [a3] "=&v"(a3),
                  [u0] "=&v"(u0), [u1] "=&v"(u1),
                  [k1] "+v"(k1[j]), [k2] "+v"(k2[j]), [gmax] "+v"(gmax)
                : [gx] "v"(gb.x), [gy] "v"(gb.y), [gz] "v"(gb.z), [gw] "v"(gb.w),
                  [ga] "v"(ga), [px1] "v"(px1[j]), [py1] "v"(py1[j]),
                  [px2] "v"(px2[j]), [py2] "v"(py2[j]), [pa] "v"(pa[j]),
                  [tb] "v"(tb[j]), [gid] "v"(gid),
                  [smp] "s"(0xFFFFFFC0u), [smg] "s"(0xFFFFFC00u));
        }
        // quad reduce via LDS-pipe swizzles (xor1, xor2) — off the VALU critical resource
        unsigned int o1 = (unsigned int)__builtin_amdgcn_ds_swizzle((int)gmax, 0x041F);
        gmax = max(gmax, o1);
        unsigned int o2 = (unsigned int)__builtin_amdgcn_ds_swizzle((int)gmax, 0x081F);
        gmax = max(gmax, o2);
        if (storer) kgrid[g * ROW + (tid >> 2)] = gmax;
    }

    // per-prior epilogue: default contribution assumes NO override (bi=i1 -> rep=i2)
    float contrib = 0.0f;
    unsigned int np = 0;
#pragma unroll
    for (int j = 0; j < PPT; j++) {
        int p = base + tid + 256 * j;
        unsigned int i2 = 63u - (k2[j] & 63u);
        // r >= 1/3  <=>  IoU >= 0.5 ; truncated-key threshold (bits(1/3f) & ~0x3F)
        bool pos = (k1[j] >= 0x3EAAAA80u);
        if (p < P_ && pos) {
            float4 pr = ((const float4*)priors)[p];               // L1-hot reload
            float4 l  = ((const float4*)pred_loc)[(size_t)b * P_ + p];
            contrib += loss_term(pr, l, sbox[i2], sga[i2]);
            np++;
        }
    }

    const int lane = tid & 63, wv = tid >> 6;
    for (int off = 32; off; off >>= 1) {
        contrib += __shfl_down(contrib, off, 64);
        np      += __shfl_down(np, off, 64);
    }
    if (lane == 0) { rs[wv] = contrib; rn[wv] = np; }
    __syncthreads();  // kgrid + rs/rn visible

    // per-gt argmax within block: 4 readers per gt scan 16 entries each
    if (tid < 192) {
        int g = tid >> 2, qq = tid & 3;
        const uint4* row = (const uint4*)&kgrid[g * ROW + qq * 16];
        unsigned int m = 0u;
#pragma unroll
        for (int i = 0; i < 4; i++) {
            uint4 v = row[i];
            m = max(max(m, v.x), max(v.y, max(v.z, v.w)));
        }
        pmax[g][qq] = m;
    }
    __syncthreads();

    if (tid < G_) {
        unsigned int w = max(max(pmax[tid][0], pmax[tid][1]),
                             max(pmax[tid][2], pmax[tid][3]));
        int p = base + 1023 - (int)(w & 0x3FFu);
        p = min(p, P_ - 1);  // defensive; unreachable via tie-break
        float4 pr = ((const float4*)priors)[p];
        float hx = pr.z * 0.5f, hy = pr.w * 0.5f;
        float qx1 = pr.x - hx, qy1 = pr.y - hy, qx2 = pr.x + hx, qy2 = pr.y + hy;
        float pae = (qx2 - qx1) * (qy2 - qy1);
        float4 gb = sbox[tid];
        float ix1 = fmaxf(gb.x, qx1), iy1 = fmaxf(gb.y, qy1);
        float ix2 = fminf(gb.z, qx2), iy2 = fminf(gb.w, qy2);
        float iw = fmaxf(ix2 - ix1, 0.0f), ih = fmaxf(iy2 - iy1, 0.0f);
        float inter = iw * ih;
        // exact (bit-stable across blocks) IoU-form key for cross-block comparison
        float v = inter * frcp(sga[tid] + pae - inter);
        // layout [b][g][chunk]: fix kernel reads each (b,g)'s 32 keys contiguously;
        // plain store (every slot written every call -> no init/memset needed)
        bkey[((size_t)b * G_ + tid) * NCH + blockIdx.x] =
            ((unsigned long long)__float_as_uint(v) << 32) |
            (unsigned long long)(0xFFFFFFFFu - (unsigned)p);
    }

    if (tid == 0) {
        pl[b * NCH + blockIdx.x] = rs[0] + rs[1] + rs[2] + rs[3];
        pn[b * NCH + blockIdx.x] = rn[0] + rn[1] + rn[2] + rn[3];
    }
}

// ---------------- K2: per-image bkey reduce + override corrections + pl/pn fold -------------
// Recomputes the best prior's top-2 keys bit-identically (max / second-max over 48 distinct
// keys is order-independent; fmax/fmin/rcp/med3 are deterministic), so mrec isn't needed.
// Also folds this image's pl/pn chunk partials so final_kernel only reduces 64 entries.
__global__ __launch_bounds__(64) void fix_kernel(
    const float* __restrict__ pred_loc, const float* __restrict__ priors,
    const float* __restrict__ gt, const unsigned long long* __restrict__ bkey,
    const float* __restrict__ pl, const unsigned int* __restrict__ pn,
    double* __restrict__ corrl, unsigned int* __restrict__ corrn) {
    const int b = blockIdx.x, t = threadIdx.x;
    __shared__ float4 sbox[G_];
    __shared__ float  sga[G_];
    __shared__ int sp[G_];

    if (t < G_) {
        const float* q = gt + ((size_t)b * G_ + t) * 5;
        float x1 = q[0], y1 = q[1], x2 = q[2], y2 = q[3];
        sbox[t] = make_float4(x1, y1, x2, y2);
        sga[t]  = (x2 - x1) * (y2 - y1);
    }
    // fold this image's chunk partials (NCH == 32 <= 64 threads)
    float  pls = 0.0f;
    unsigned int pns = 0u;
    if (t < NCH) { pls = pl[b * NCH + t]; pns = pn[b * NCH + t]; }

    int p = -1;
    if (t < G_) {
        const unsigned long long* row = bkey + ((size_t)b * G_ + t) * NCH;
        unsigned long long m = 0ull;
#pragma unroll
        for (int c = 0; c < NCH; c++) m = max(m, row[c]);
        p = (int)(0xFFFFFFFFu - (unsigned)(m & 0xFFFFFFFFull));
        sp[t] = p;
    }
    __syncthreads();

    double delta = 0.0;
    unsigned int dn = 0;
    if (t < G_) {
        // last-write-wins: t is alive iff no larger t' shares the same best prior
        bool alive = true;
        for (int d = t + 1; d < G_; d++)
            if (sp[d] == p) alive = false;
        if (alive) {
            // recompute prior p's top-2 over all gts (bit-identical to match's tournament)
            float4 pr = ((const float4*)priors)[p];
            float hx = pr.z * 0.5f, hy = pr.w * 0.5f;
            float px1 = pr.x - hx, py1 = pr.y - hy, px2 = pr.x + hx, py2 = pr.y + hy;
            float pa = (px2 - px1) * (py2 - py1);
            unsigned int k1 = 0u, k2 = 0u;
#pragma unroll 8
            for (int g = 0; g < G_; g++) {
                float4 gb = sbox[g];
                float ix1 = fmaxf(gb.x, px1), iy1 = fmaxf(gb.y, py1);
                float ix2 = fminf(gb.z, px2), iy2 = fminf(gb.w, py2);
                float iw = fmaxf(ix2 - ix1, 0.0f), ih = fmaxf(iy2 - iy1, 0.0f);
                float inter = iw * ih;
                float r = inter * frcp(sga[g] + pa);
                unsigned int vb = __float_as_uint(r);
                unsigned int pk = (vb & 0xFFFFFFC0u) | (unsigned)(63 - g);
                unsigned int nk2;
                asm("v_med3_u32 %0, %1, %2, %3" : "=v"(nk2) : "v"(k1), "v"(k2), "v"(pk));
                k2 = nk2;
                k1 = max(k1, pk);
            }
            int i1 = (int)(63u - (k1 & 63u)), i2 = (int)(63u - (k2 & 63u));
            bool pos0 = (k1 >= 0x3EAAAA80u);
            int ri = (t == i1) ? i2 : i1;   // override bi=t -> rep flips to i1 unless t==i1
            float4 l = ((const float4*)pred_loc)[(size_t)b * P_ + p];
            float cnew = loss_term(pr, l, sbox[ri], sga[ri]);
            float cold = 0.0f;
            if (pos0) {
                cold = loss_term(pr, l, sbox[i2], sga[i2]);   // cancels match's default term
            } else {
                dn = 1;                                        // prior newly positive
            }
            delta = (double)cnew - (double)cold;
        }
    }
    double acc = delta + (double)pls;
    unsigned int nn = dn + pns;
    for (int off = 32; off; off >>= 1) {
        acc += __shfl_down(acc, off, 64);
        nn  += __shfl_down(nn, off, 64);
    }
    if (t == 0) { corrl[b] = acc; corrn[b] = nn; }
}

// ---------------- K3: final reduction (64 per-image totals -> scalar) -----------------------
__global__ __launch_bounds__(64) void final_kernel(
    const double* __restrict__ corrl, const unsigned int* __restrict__ corrn,
    float* __restrict__ out) {
    const int t = threadIdx.x;
    double acc = corrl[t];        // B_ == 64 == blockDim
    unsigned int n = corrn[t];
    for (int off = 32; off; off >>= 1) {
        acc += __shfl_down(acc, off, 64);
        n   += __shfl_down(n, off, 64);
    }
    if (t == 0) out[0] = (float)(acc / (double)n);
}

extern "C" void kernel_launch(void* const* d_in, const int* in_sizes, int n_in,
                              void* d_out, int out_size, void* d_ws, size_t ws_size,
                              hipStream_t stream) {
    const float* pred_loc = (const float*)d_in[0];  // [B,P,4]
    const float* priors   = (const float*)d_in[1];  // [P,4]
    const float* gt       = (const float*)d_in[2];  // [B,G,5]
    float* out = (float*)d_out;

    char* ws = (char*)d_ws;
    unsigned long long* bkey = (unsigned long long*)ws;                   // 786432 B
    float*        pl    = (float*)(ws + 786432);                          // 8192 B
    unsigned int* pn    = (unsigned int*)(ws + 794624);                   // 8192 B
    double*       corrl = (double*)(ws + 802816);                         // 512 B
    unsigned int* corrn = (unsigned int*)(ws + 803328);                   // 256 B

    dim3 g1(NCH, B_);
    match_kernel<<<g1, 256, 0, stream>>>(pred_loc, priors, gt, bkey, pl, pn);

    fix_kernel<<<B_, 64, 0, stream>>>(pred_loc, priors, gt, bkey, pl, pn, corrl, corrn);

    final_kernel<<<1, 64, 0, stream>>>(corrl, corrn, out);
}